// Round 1
// baseline (4373.410 us; speedup 1.0000x reference)
//
#include <hip/hip_runtime.h>
#include <math.h>

#define N_NODES 100000
#define N_EDGES 1600000
#define F_IN 92
#define E_IN 50
#define D 64
#define N_LAYERS 3
#define N_GRAPHS 512
#define BN_EPS 1e-5f

__device__ __forceinline__ float silu_f(float x) {
    return x / (1.0f + __expf(-x));
}

__device__ __forceinline__ float bcast_f(float v, int lane) {
    return __int_as_float(__builtin_amdgcn_readlane(__float_as_int(v), lane));
}

// ---------------- CSR build ----------------
__global__ __launch_bounds__(256) void hist_kernel(
    const int* __restrict__ dst, int* __restrict__ deg) {
    for (int e = blockIdx.x * 256 + threadIdx.x; e < N_EDGES; e += gridDim.x * 256)
        atomicAdd(&deg[dst[e]], 1);
}

__global__ __launch_bounds__(1024) void scan_kernel(
    const int* __restrict__ deg, int* __restrict__ row_start,
    int* __restrict__ cursor) {
    __shared__ int part[1024];
    int t = threadIdx.x;
    const int CH = (N_NODES + 1023) / 1024;
    int lo = t * CH, hi = min(lo + CH, N_NODES);
    int s = 0;
    for (int i = lo; i < hi; ++i) s += deg[i];
    part[t] = s;
    __syncthreads();
    for (int off = 1; off < 1024; off <<= 1) {
        int v = (t >= off) ? part[t - off] : 0;
        __syncthreads();
        part[t] += v;
        __syncthreads();
    }
    int base = (t == 0) ? 0 : part[t - 1];
    for (int i = lo; i < hi; ++i) {
        int dg = deg[i];
        row_start[i] = base;
        cursor[i] = base;
        base += dg;
    }
    if (t == 1023) row_start[N_NODES] = base;
}

// fallback path (no workspace for permuted edges): plain csr scatter
__global__ __launch_bounds__(256) void scatter_kernel(
    const int* __restrict__ dst, int* __restrict__ cursor,
    int* __restrict__ csr) {
    for (int e = blockIdx.x * 256 + threadIdx.x; e < N_EDGES; e += gridDim.x * 256) {
        int pos = atomicAdd(&cursor[dst[e]], 1);
        csr[pos] = e;
    }
}

// Fused scatter + permute: one wave per edge, SEQUENTIAL edge order.
// Read ea row coalesced+sequential; write to its dst-sorted slot (random pos,
// but coalesced 200B store -> fire-and-forget, L2 write-back absorbs).
// Replaces the old scatter_kernel + perm_kernel (random-READ permutation,
// which ran at 18% of HBM peak due to dependent gathers + DRAM row thrash).
__global__ __launch_bounds__(256) void scatter_perm_kernel(
    const int* __restrict__ srcIdx, const int* __restrict__ dstIdx,
    const float* __restrict__ ea, int* __restrict__ cursor,
    float* __restrict__ ea_s, int* __restrict__ src_s) {
    int d = threadIdx.x;
    int e = blockIdx.x * 4 + threadIdx.y;
    if (e >= N_EDGES) return;
    int pos = 0;
    if (d == 0) pos = atomicAdd(&cursor[dstIdx[e]], 1);
    pos = __builtin_amdgcn_readlane(pos, 0);
    if (d == 0) src_s[pos] = srcIdx[e];
    if (d < E_IN) ea_s[(long)pos * E_IN + d] = ea[(long)e * E_IN + d];
}

// ---------------- dense stages ----------------
// h = silu(x @ pre_w + pre_b)
__global__ __launch_bounds__(256) void pre_fc_kernel(
    const float* __restrict__ x, const float* __restrict__ w,
    const float* __restrict__ b, float* __restrict__ h) {
    __shared__ float xs[4][F_IN];
    int d = threadIdx.x, yy = threadIdx.y;
    int node = blockIdx.x * 4 + yy;
    if (node < N_NODES) {
        const float* xrow = x + (long)node * F_IN;
        for (int i = d; i < F_IN; i += 64) xs[yy][i] = xrow[i];
    }
    __syncthreads();
    if (node >= N_NODES) return;
    float acc = b[d];
#pragma unroll 4
    for (int i = 0; i < F_IN; ++i) acc = fmaf(xs[yy][i], w[i * D + d], acc);
    h[(long)node * D + d] = silu_f(acc);
}

// Optional-BN-normalize input, then 4 fused GEMMs: k,q,v + skip(hnew=h@Ws+bias)
template <bool BN>
__global__ __launch_bounds__(256) void proj_kernel(
    const float* __restrict__ hin, const float* __restrict__ stats,
    const float* __restrict__ gamma, const float* __restrict__ beta,
    const float* __restrict__ Wk, const float* __restrict__ bk,
    const float* __restrict__ Wq, const float* __restrict__ bq,
    const float* __restrict__ Wv, const float* __restrict__ bv,
    const float* __restrict__ Ws, const float* __restrict__ cbias,
    float* __restrict__ ko, float* __restrict__ qo, float* __restrict__ vo,
    float* __restrict__ hnew) {
    __shared__ float hs[4][D];
    int d = threadIdx.x, yy = threadIdx.y;
    int node = blockIdx.x * 4 + yy;
    if (node < N_NODES) {
        float xv = hin[(long)node * D + d];
        if (BN) {
            const float invN = 1.0f / (float)N_NODES;
            float mean = stats[d] * invN;
            float var = stats[D + d] * invN - mean * mean;
            float sc = rsqrtf(var + BN_EPS) * gamma[d];
            xv = (xv - mean) * sc + beta[d];
        }
        hs[yy][d] = xv;
    }
    __syncthreads();
    if (node >= N_NODES) return;
    float ak = bk[d], aq = bq[d], av = bv[d], as = cbias[d];
#pragma unroll 8
    for (int i = 0; i < D; ++i) {
        float hv = hs[yy][i];
        ak = fmaf(hv, Wk[i * D + d], ak);
        aq = fmaf(hv, Wq[i * D + d], aq);
        av = fmaf(hv, Wv[i * D + d], av);
        as = fmaf(hv, Ws[i * D + d], as);
    }
    long off = (long)node * D + d;
    ko[off] = ak; qo[off] = aq; vo[off] = av; hnew[off] = as;
}

// One wave per node, pipelined edge loop. hnew[node] += sum_e silu(k+q+2e)*(v+e)
// PERM: ea/src pre-sorted by dst (indexed by CSR position p). !PERM: indexed by e=csr[p].
template <bool PERM>
__global__ __launch_bounds__(256) void gather_kernel(
    const float* __restrict__ ea, const int* __restrict__ srcArr,
    const int* __restrict__ csr, const int* __restrict__ row_start,
    const float* __restrict__ We,
    const float* __restrict__ kb, const float* __restrict__ qb,
    const float* __restrict__ vb, float* __restrict__ hnew) {
    int d = threadIdx.x;
    int node = blockIdx.x * 4 + threadIdx.y;
    if (node >= N_NODES) return;
    float WeReg[E_IN];  // We column d held in registers
#pragma unroll
    for (int i = 0; i < E_IN; ++i) WeReg[i] = We[i * D + d];
    int lo = row_start[node], hi = row_start[node + 1];
    float kv = kb[(long)node * D + d];
    float acc = 0.f;
    if (PERM) {
        // PERM path: edge-row address is wave-uniform (base+j). Read the row
        // via uniform vector loads (13x dwordx4 broadcast) instead of the
        // per-lane load + 50x v_readlane broadcast dance. A distance-2
        // per-lane prefetch keeps the HBM fetch asynchronous; the er loads
        // then hit L1. vzero keeps the address on the vector path (no SMEM
        // promotion, which would bypass the L1 the prefetch warmed).
        int vzero;
        asm("v_mov_b32 %0, 0" : "=v"(vzero));
        for (int base = lo; base < hi; base += 64) {
            int cnt = min(hi - base, 64);
            int s_l = 0;
            if (d < cnt) s_l = srcArr[base + d];
            int s_c = __builtin_amdgcn_readlane(s_l, 0);
            float q_c = qb[(long)s_c * D + d];
            float v_c = vb[(long)s_c * D + d];
            float pf_a = 0.f, pf_b = 0.f;
            if (d < E_IN) {
                pf_a = ea[(long)base * E_IN + d];
                if (cnt > 1) pf_b = ea[(long)(base + 1) * E_IN + d];
            }
            for (int j = 0; j < cnt; ++j) {
                float q_n = 0.f, v_n = 0.f;
                if (j + 1 < cnt) {
                    int s_n = __builtin_amdgcn_readlane(s_l, j + 1);
                    q_n = qb[(long)s_n * D + d];
                    v_n = vb[(long)s_n * D + d];
                }
                float pf_c = (d < E_IN && j + 2 < cnt)
                                 ? ea[(long)(base + j + 2) * E_IN + d] : 0.f;
                const float* er = ea + (long)(base + j) * E_IN + vzero;
                float ed0 = 0.f, ed1 = 0.f;
#pragma unroll
                for (int i = 0; i < E_IN; i += 2) {
                    ed0 = fmaf(er[i], WeReg[i], ed0);
                    ed1 = fmaf(er[i + 1], WeReg[i + 1], ed1);
                }
                float ed = ed0 + ed1;
                float gate = silu_f(kv + q_c + 2.0f * ed);
                acc = fmaf(gate, v_c + ed, acc);
                // retire oldest prefetch: its load is 2 iterations old, so the
                // implied vmcnt wait is already satisfied (no stall).
                asm volatile("" :: "v"(pf_a));
                pf_a = pf_b; pf_b = pf_c;
                q_c = q_n; v_c = v_n;
            }
        }
    } else {
        for (int base = lo; base < hi; base += 64) {
            int cnt = min(hi - base, 64);
            int e_l = 0, s_l = 0;
            if (d < cnt) {
                int p = base + d;
                e_l = csr[p];
                s_l = srcArr[e_l];
            }
            int s_c = __builtin_amdgcn_readlane(s_l, 0);
            int r_c = __builtin_amdgcn_readlane(e_l, 0);
            float q_c = qb[(long)s_c * D + d];
            float v_c = vb[(long)s_c * D + d];
            float e_c = (d < E_IN) ? ea[(long)r_c * E_IN + d] : 0.f;
            for (int j = 0; j < cnt; ++j) {
                float q_n = 0.f, v_n = 0.f, e_n = 0.f;
                if (j + 1 < cnt) {
                    int s_n = __builtin_amdgcn_readlane(s_l, j + 1);
                    int r_n = __builtin_amdgcn_readlane(e_l, j + 1);
                    q_n = qb[(long)s_n * D + d];
                    v_n = vb[(long)s_n * D + d];
                    e_n = (d < E_IN) ? ea[(long)r_n * E_IN + d] : 0.f;
                }
                float ed0 = 0.f, ed1 = 0.f;
#pragma unroll
                for (int i = 0; i < E_IN; i += 2) {
                    ed0 = fmaf(bcast_f(e_c, i), WeReg[i], ed0);
                    ed1 = fmaf(bcast_f(e_c, i + 1), WeReg[i + 1], ed1);
                }
                float ed = ed0 + ed1;
                float gate = silu_f(kv + q_c + 2.0f * ed);
                acc = fmaf(gate, v_c + ed, acc);
                q_c = q_n; v_c = v_n; e_c = e_n;
            }
        }
    }
    long off = (long)node * D + d;
    hnew[off] += acc;
}

// per-column sum & sumsq
__global__ __launch_bounds__(256) void bn_stats_kernel(
    const float* __restrict__ hnew, float* __restrict__ stats) {
    int d = threadIdx.x, yy = threadIdx.y;
    float s = 0.f, s2 = 0.f;
    for (int n = blockIdx.x * 4 + yy; n < N_NODES; n += gridDim.x * 4) {
        float v = hnew[(long)n * D + d];
        s += v;
        s2 = fmaf(v, v, s2);
    }
    __shared__ float ls[4][D], ls2[4][D];
    ls[yy][d] = s; ls2[yy][d] = s2;
    __syncthreads();
    if (yy == 0) {
        atomicAdd(&stats[d],     ls[0][d] + ls[1][d] + ls[2][d] + ls[3][d]);
        atomicAdd(&stats[D + d], ls2[0][d] + ls2[1][d] + ls2[2][d] + ls2[3][d]);
    }
}

__global__ __launch_bounds__(256) void graph_bounds_kernel(
    const int* __restrict__ batch, int* __restrict__ start) {
    int n = blockIdx.x * 256 + threadIdx.x;
    if (n >= N_NODES) return;
    int b = batch[n];
    if (n == 0) {
        for (int g = 0; g <= b; ++g) start[g] = 0;
    } else {
        int p = batch[n - 1];
        for (int g = p + 1; g <= b; ++g) start[g] = n;
    }
    if (n == N_NODES - 1) {
        for (int g = b + 1; g <= N_GRAPHS; ++g) start[g] = N_NODES;
    }
}

// mean-pool(hnew) -> fused final-BN affine -> post FC + silu -> head
__global__ __launch_bounds__(256) void pool_head_kernel(
    const float* __restrict__ hnew, const int* __restrict__ start,
    const float* __restrict__ stats, const float* __restrict__ gamma,
    const float* __restrict__ beta,
    const float* __restrict__ pw, const float* __restrict__ pb,
    const float* __restrict__ ow, const float* __restrict__ ob,
    float* __restrict__ out) {
    int g = blockIdx.x;
    int d = threadIdx.x, yy = threadIdx.y;
    int lo = start[g], hi = start[g + 1];
    float s = 0.f;
    for (int n = lo + yy; n < hi; n += 4) s += hnew[(long)n * D + d];
    __shared__ float ls[4][D];
    ls[yy][d] = s;
    __syncthreads();
    __shared__ float grow[D];
    if (yy == 0) {
        float tot = ls[0][d] + ls[1][d] + ls[2][d] + ls[3][d];
        float gd = 0.f;
        if (hi > lo) {  // BN is affine; affine(mean) == mean(affine). empty graph -> 0
            float m = tot / (float)(hi - lo);
            const float invN = 1.0f / (float)N_NODES;
            float mean = stats[d] * invN;
            float var = stats[D + d] * invN - mean * mean;
            float sc = rsqrtf(var + BN_EPS) * gamma[d];
            gd = (m - mean) * sc + beta[d];
        }
        grow[d] = gd;
    }
    __syncthreads();
    if (yy != 0) return;
    float accp = pb[d];
#pragma unroll 8
    for (int i = 0; i < D; ++i) accp = fmaf(grow[i], pw[i * D + d], accp);
    float sv = silu_f(accp) * ow[d];
    for (int off = 32; off > 0; off >>= 1) sv += __shfl_down(sv, off);
    if (d == 0) out[g] = sv + ob[0];
}

extern "C" void kernel_launch(void* const* d_in, const int* in_sizes, int n_in,
                              void* d_out, int out_size, void* d_ws, size_t ws_size,
                              hipStream_t stream) {
    const float* x        = (const float*)d_in[0];
    const int*   ei       = (const int*)d_in[1];
    const float* ea       = (const float*)d_in[2];
    const int*   batch    = (const int*)d_in[3];
    const float* pre_w    = (const float*)d_in[4];
    const float* pre_b    = (const float*)d_in[5];
    const float* Wk       = (const float*)d_in[6];
    const float* bk       = (const float*)d_in[7];
    const float* Wq       = (const float*)d_in[8];
    const float* bq       = (const float*)d_in[9];
    const float* Wv       = (const float*)d_in[10];
    const float* bv       = (const float*)d_in[11];
    const float* We       = (const float*)d_in[12];
    const float* Wskip    = (const float*)d_in[13];
    const float* conv_bias= (const float*)d_in[14];
    const float* bn_gamma = (const float*)d_in[15];
    const float* bn_beta  = (const float*)d_in[16];
    const float* post_w   = (const float*)d_in[17];
    const float* post_b   = (const float*)d_in[18];
    const float* out_w    = (const float*)d_in[19];
    const float* out_b    = (const float*)d_in[20];

    float* ws = (float*)d_ws;
    const size_t NH = (size_t)N_NODES * D;
    float* bufA  = ws;
    float* bufB  = ws + NH;
    float* kb    = ws + 2 * NH;
    float* qb    = ws + 3 * NH;
    float* vb    = ws + 4 * NH;
    float* stats = ws + 5 * NH;                          // 3 * 2*D floats
    int*   start     = (int*)(stats + 6 * D);            // N_GRAPHS+1
    int*   deg       = start + (N_GRAPHS + 1);           // N_NODES
    int*   row_start = deg + N_NODES;                    // N_NODES+1
    int*   cursor    = row_start + (N_NODES + 1);        // N_NODES
    int*   csr       = cursor + N_NODES;                 // N_EDGES (fallback only)
    // optional permuted-edge region (aligned)
    size_t off_b = (size_t)((char*)(csr + N_EDGES) - (char*)d_ws);
    off_b = (off_b + 63) & ~(size_t)63;
    float* ea_s  = (float*)((char*)d_ws + off_b);        // N_EDGES * E_IN
    int*   src_s = (int*)(ea_s + (size_t)N_EDGES * E_IN);// N_EDGES
    size_t need  = (size_t)((char*)(src_s + N_EDGES) - (char*)d_ws);
    const bool use_perm = ws_size >= need;

    const int* srcIdx = ei;
    const int* dstIdx = ei + N_EDGES;

    dim3 blk(64, 4);
    const int NB_N = (N_NODES + 3) / 4;

    // CSR build
    hipMemsetAsync(deg, 0, N_NODES * sizeof(int), stream);
    hipMemsetAsync(stats, 0, 6 * D * sizeof(float), stream);
    hist_kernel<<<1024, 256, 0, stream>>>(dstIdx, deg);
    scan_kernel<<<1, 1024, 0, stream>>>(deg, row_start, cursor);
    if (use_perm)
        scatter_perm_kernel<<<(N_EDGES + 3) / 4, blk, 0, stream>>>(
            srcIdx, dstIdx, ea, cursor, ea_s, src_s);
    else
        scatter_kernel<<<1024, 256, 0, stream>>>(dstIdx, cursor, csr);

    pre_fc_kernel<<<NB_N, blk, 0, stream>>>(x, pre_w, pre_b, bufA);

    float* hin = bufA;
    float* hout = bufB;
    for (int l = 0; l < N_LAYERS; ++l) {
        if (l == 0)
            proj_kernel<false><<<NB_N, blk, 0, stream>>>(
                hin, nullptr, nullptr, nullptr,
                Wk + l * D * D, bk + l * D, Wq + l * D * D, bq + l * D,
                Wv + l * D * D, bv + l * D, Wskip + l * D * D, conv_bias + l * D,
                kb, qb, vb, hout);
        else
            proj_kernel<true><<<NB_N, blk, 0, stream>>>(
                hin, stats + (l - 1) * 2 * D, bn_gamma + (l - 1) * D, bn_beta + (l - 1) * D,
                Wk + l * D * D, bk + l * D, Wq + l * D * D, bq + l * D,
                Wv + l * D * D, bv + l * D, Wskip + l * D * D, conv_bias + l * D,
                kb, qb, vb, hout);
        if (use_perm)
            gather_kernel<true><<<NB_N, blk, 0, stream>>>(
                ea_s, src_s, csr, row_start, We + l * E_IN * D, kb, qb, vb, hout);
        else
            gather_kernel<false><<<NB_N, blk, 0, stream>>>(
                ea, srcIdx, csr, row_start, We + l * E_IN * D, kb, qb, vb, hout);
        bn_stats_kernel<<<256, blk, 0, stream>>>(hout, stats + l * 2 * D);
        float* t = hin; hin = hout; hout = t;
    }

    graph_bounds_kernel<<<(N_NODES + 255) / 256, 256, 0, stream>>>(batch, start);
    // hin now points to the last layer's hnew
    pool_head_kernel<<<N_GRAPHS, blk, 0, stream>>>(
        hin, start, stats + (N_LAYERS - 1) * 2 * D,
        bn_gamma + (N_LAYERS - 1) * D, bn_beta + (N_LAYERS - 1) * D,
        post_w, post_b, out_w, out_b, (float*)d_out);
}

// Round 2
// 3270.320 us; speedup vs baseline: 1.3373x; 1.3373x over previous
//
#include <hip/hip_runtime.h>
#include <math.h>

#define N_NODES 100000
#define N_EDGES 1600000
#define F_IN 92
#define E_IN 50
#define D 64
#define N_LAYERS 3
#define N_GRAPHS 512
#define BN_EPS 1e-5f

#define SCAN_BLK 1024
#define SCAN_NCH ((N_NODES + SCAN_BLK - 1) / SCAN_BLK)  // 98

__device__ __forceinline__ float silu_f(float x) {
    return x / (1.0f + __expf(-x));
}

__device__ __forceinline__ float bcast_f(float v, int lane) {
    return __int_as_float(__builtin_amdgcn_readlane(__float_as_int(v), lane));
}

// ---------------- CSR build ----------------
__global__ __launch_bounds__(256) void hist_kernel(
    const int* __restrict__ dst, int* __restrict__ deg) {
    for (int e = blockIdx.x * 256 + threadIdx.x; e < N_EDGES; e += gridDim.x * 256)
        atomicAdd(&deg[dst[e]], 1);
}

// 3-phase multi-block exclusive scan (replaces the single-block latency-bound scan)
__global__ __launch_bounds__(SCAN_BLK) void scan_sum_kernel(
    const int* __restrict__ deg, int* __restrict__ partials) {
    int b = blockIdx.x, t = threadIdx.x;
    int i = b * SCAN_BLK + t;
    int v = (i < N_NODES) ? deg[i] : 0;
    __shared__ int wsum[16];
    for (int off = 32; off > 0; off >>= 1) v += __shfl_down(v, off);
    if ((t & 63) == 0) wsum[t >> 6] = v;
    __syncthreads();
    if (t < 16) {
        int s = wsum[t];
        for (int off = 8; off > 0; off >>= 1) s += __shfl_down(s, off);
        if (t == 0) partials[b] = s;
    }
}

__global__ __launch_bounds__(128) void scan_part_kernel(int* __restrict__ partials) {
    int t = threadIdx.x;
    __shared__ int sh[128];
    sh[t] = (t < SCAN_NCH) ? partials[t] : 0;
    __syncthreads();
    for (int off = 1; off < 128; off <<= 1) {
        int v = (t >= off) ? sh[t - off] : 0;
        __syncthreads();
        sh[t] += v;
        __syncthreads();
    }
    if (t < SCAN_NCH) partials[t] = (t == 0) ? 0 : sh[t - 1];  // exclusive
}

__global__ __launch_bounds__(SCAN_BLK) void scan_write_kernel(
    const int* __restrict__ deg, const int* __restrict__ partials,
    int* __restrict__ row_start, int* __restrict__ cursor) {
    int b = blockIdx.x, t = threadIdx.x;
    int i = b * SCAN_BLK + t;
    int v = (i < N_NODES) ? deg[i] : 0;
    __shared__ int sh[SCAN_BLK];
    sh[t] = v;
    __syncthreads();
    for (int off = 1; off < SCAN_BLK; off <<= 1) {
        int x = (t >= off) ? sh[t - off] : 0;
        __syncthreads();
        sh[t] += x;
        __syncthreads();
    }
    int excl = partials[b] + sh[t] - v;
    if (i < N_NODES) { row_start[i] = excl; cursor[i] = excl; }
    if (i == N_NODES - 1) row_start[N_NODES] = excl + v;
}

// fallback path (no workspace for permuted edges): plain csr scatter
__global__ __launch_bounds__(256) void scatter_kernel(
    const int* __restrict__ dst, int* __restrict__ cursor,
    int* __restrict__ csr) {
    for (int e = blockIdx.x * 256 + threadIdx.x; e < N_EDGES; e += gridDim.x * 256) {
        int pos = atomicAdd(&cursor[dst[e]], 1);
        csr[pos] = e;
    }
}

// Fused scatter + permute: one wave per edge, SEQUENTIAL edge order.
// Sequential coalesced read, random (but row-coalesced) write.
template <int STRIDE>
__global__ __launch_bounds__(256) void scatter_perm_kernel(
    const int* __restrict__ srcIdx, const int* __restrict__ dstIdx,
    const float* __restrict__ ea, int* __restrict__ cursor,
    float* __restrict__ ea_s, int* __restrict__ src_s) {
    int d = threadIdx.x;
    int e = blockIdx.x * 4 + threadIdx.y;
    if (e >= N_EDGES) return;
    int pos = 0;
    if (d == 0) pos = atomicAdd(&cursor[dstIdx[e]], 1);
    pos = __builtin_amdgcn_readlane(pos, 0);
    if (d == 0) src_s[pos] = srcIdx[e];
    if (d < E_IN) ea_s[(long)pos * STRIDE + d] = ea[(long)e * E_IN + d];
}

// ---------------- dense stages ----------------
// h = silu(x @ pre_w + pre_b)
__global__ __launch_bounds__(256) void pre_fc_kernel(
    const float* __restrict__ x, const float* __restrict__ w,
    const float* __restrict__ b, float* __restrict__ h) {
    __shared__ float xs[4][F_IN];
    int d = threadIdx.x, yy = threadIdx.y;
    int node = blockIdx.x * 4 + yy;
    if (node < N_NODES) {
        const float* xrow = x + (long)node * F_IN;
        for (int i = d; i < F_IN; i += 64) xs[yy][i] = xrow[i];
    }
    __syncthreads();
    if (node >= N_NODES) return;
    float acc = b[d];
#pragma unroll 4
    for (int i = 0; i < F_IN; ++i) acc = fmaf(xs[yy][i], w[i * D + d], acc);
    h[(long)node * D + d] = silu_f(acc);
}

// Optional-BN-normalize input, then 4 fused GEMMs: k,q,v + skip(hnew=h@Ws+bias)
template <bool BN>
__global__ __launch_bounds__(256) void proj_kernel(
    const float* __restrict__ hin, const float* __restrict__ stats,
    const float* __restrict__ gamma, const float* __restrict__ beta,
    const float* __restrict__ Wk, const float* __restrict__ bk,
    const float* __restrict__ Wq, const float* __restrict__ bq,
    const float* __restrict__ Wv, const float* __restrict__ bv,
    const float* __restrict__ Ws, const float* __restrict__ cbias,
    float* __restrict__ ko, float* __restrict__ qo, float* __restrict__ vo,
    float* __restrict__ hnew) {
    __shared__ float hs[4][D];
    int d = threadIdx.x, yy = threadIdx.y;
    int node = blockIdx.x * 4 + yy;
    if (node < N_NODES) {
        float xv = hin[(long)node * D + d];
        if (BN) {
            const float invN = 1.0f / (float)N_NODES;
            float mean = stats[d] * invN;
            float var = stats[D + d] * invN - mean * mean;
            float sc = rsqrtf(var + BN_EPS) * gamma[d];
            xv = (xv - mean) * sc + beta[d];
        }
        hs[yy][d] = xv;
    }
    __syncthreads();
    if (node >= N_NODES) return;
    float ak = bk[d], aq = bq[d], av = bv[d], as = cbias[d];
#pragma unroll 8
    for (int i = 0; i < D; ++i) {
        float hv = hs[yy][i];
        ak = fmaf(hv, Wk[i * D + d], ak);
        aq = fmaf(hv, Wq[i * D + d], aq);
        av = fmaf(hv, Wv[i * D + d], av);
        as = fmaf(hv, Ws[i * D + d], as);
    }
    long off = (long)node * D + d;
    ko[off] = ak; qo[off] = aq; vo[off] = av; hnew[off] = as;
}

// Edge-embedding GEMM: em[p-c0][d] = sum_i ea_s[p][i] * We[i][d], p in [c0,c1).
// Lane owns one edge: 64 accumulators in VGPRs, We broadcast via SGPR loads
// (uniform compile-time-indexed -> s_load; 1 SGPR operand per v_fma is free).
// Pure-FLOP inner loop: no readlane, no LDS, no per-edge VMEM waits.
__global__ __launch_bounds__(256) void edge_emb_kernel(
    const float* __restrict__ ea_s, const float* __restrict__ We,
    float* __restrict__ em, int c0, int c1) {
    int p = c0 + blockIdx.x * 256 + threadIdx.x;
    if (p >= c1) return;
    const float* row = ea_s + (long)p * 64;  // 256B-aligned rows (stride 64)
    float acc[D];
#pragma unroll
    for (int d = 0; d < D; ++d) acc[d] = 0.f;
#pragma unroll
    for (int i = 0; i < E_IN; i += 2) {
        float2 ev = *reinterpret_cast<const float2*>(row + i);
#pragma unroll
        for (int d = 0; d < D; ++d) acc[d] = fmaf(ev.x, We[i * D + d], acc[d]);
#pragma unroll
        for (int d = 0; d < D; ++d) acc[d] = fmaf(ev.y, We[(i + 1) * D + d], acc[d]);
    }
    float* out = em + (long)(p - c0) * D;
#pragma unroll
    for (int d = 0; d < D; d += 4)
        *reinterpret_cast<float4*>(out + d) =
            make_float4(acc[d], acc[d + 1], acc[d + 2], acc[d + 3]);
}

// Gather with precomputed edge embedding: per edge just 3 coalesced row loads
// (em sequential; q,v gathered) + silu + 2 FMA. 2-stage pipelined.
__global__ __launch_bounds__(256) void gather_em_kernel(
    const float* __restrict__ em, const int* __restrict__ src_s,
    const int* __restrict__ row_start,
    const float* __restrict__ kb, const float* __restrict__ qb,
    const float* __restrict__ vb, float* __restrict__ hnew,
    int c0, int c1) {
    int d = threadIdx.x;
    int node = blockIdx.x * 4 + threadIdx.y;
    if (node >= N_NODES) return;
    int lo = row_start[node], hi = row_start[node + 1];
    lo = max(lo, c0); hi = min(hi, c1);
    if (lo >= hi) return;
    float kv = kb[(long)node * D + d];
    float acc = 0.f;
    for (int base = lo; base < hi; base += 64) {
        int cnt = min(hi - base, 64);
        int s_l = 0;
        if (d < cnt) s_l = src_s[base + d];
        int s_c = __builtin_amdgcn_readlane(s_l, 0);
        float q_c = qb[(long)s_c * D + d];
        float v_c = vb[(long)s_c * D + d];
        float e_c = em[(long)(base - c0) * D + d];
        for (int j = 0; j < cnt; ++j) {
            float q_n = 0.f, v_n = 0.f, e_n = 0.f;
            if (j + 1 < cnt) {
                int s_n = __builtin_amdgcn_readlane(s_l, j + 1);
                q_n = qb[(long)s_n * D + d];
                v_n = vb[(long)s_n * D + d];
                e_n = em[(long)(base + j + 1 - c0) * D + d];
            }
            float gate = silu_f(kv + q_c + 2.0f * e_c);
            acc = fmaf(gate, v_c + e_c, acc);
            q_c = q_n; v_c = v_n; e_c = e_n;
        }
    }
    long off = (long)node * D + d;
    hnew[off] += acc;
}

// Legacy one-wave-per-node gather (fallback tiers). hnew += sum_e silu(k+q+2e)*(v+e)
template <bool PERM>
__global__ __launch_bounds__(256) void gather_kernel(
    const float* __restrict__ ea, const int* __restrict__ srcArr,
    const int* __restrict__ csr, const int* __restrict__ row_start,
    const float* __restrict__ We,
    const float* __restrict__ kb, const float* __restrict__ qb,
    const float* __restrict__ vb, float* __restrict__ hnew) {
    int d = threadIdx.x;
    int node = blockIdx.x * 4 + threadIdx.y;
    if (node >= N_NODES) return;
    float WeReg[E_IN];
#pragma unroll
    for (int i = 0; i < E_IN; ++i) WeReg[i] = We[i * D + d];
    int lo = row_start[node], hi = row_start[node + 1];
    float kv = kb[(long)node * D + d];
    float acc = 0.f;
    for (int base = lo; base < hi; base += 64) {
        int cnt = min(hi - base, 64);
        int e_l = 0, s_l = 0;
        if (d < cnt) {
            int p = base + d;
            e_l = PERM ? p : csr[p];
            s_l = PERM ? srcArr[p] : srcArr[e_l];
        }
        int s_c = __builtin_amdgcn_readlane(s_l, 0);
        int r_c = PERM ? base : __builtin_amdgcn_readlane(e_l, 0);
        float q_c = qb[(long)s_c * D + d];
        float v_c = vb[(long)s_c * D + d];
        float e_c = (d < E_IN) ? ea[(long)r_c * E_IN + d] : 0.f;
        for (int j = 0; j < cnt; ++j) {
            float q_n = 0.f, v_n = 0.f, e_n = 0.f;
            if (j + 1 < cnt) {
                int s_n = __builtin_amdgcn_readlane(s_l, j + 1);
                int r_n = PERM ? (base + j + 1) : __builtin_amdgcn_readlane(e_l, j + 1);
                q_n = qb[(long)s_n * D + d];
                v_n = vb[(long)s_n * D + d];
                e_n = (d < E_IN) ? ea[(long)r_n * E_IN + d] : 0.f;
            }
            float ed0 = 0.f, ed1 = 0.f;
#pragma unroll
            for (int i = 0; i < E_IN; i += 2) {
                ed0 = fmaf(bcast_f(e_c, i), WeReg[i], ed0);
                ed1 = fmaf(bcast_f(e_c, i + 1), WeReg[i + 1], ed1);
            }
            float ed = ed0 + ed1;
            float gate = silu_f(kv + q_c + 2.0f * ed);
            acc = fmaf(gate, v_c + ed, acc);
            q_c = q_n; v_c = v_n; e_c = e_n;
        }
    }
    long off = (long)node * D + d;
    hnew[off] += acc;
}

// per-column sum & sumsq
__global__ __launch_bounds__(256) void bn_stats_kernel(
    const float* __restrict__ hnew, float* __restrict__ stats) {
    int d = threadIdx.x, yy = threadIdx.y;
    float s = 0.f, s2 = 0.f;
    for (int n = blockIdx.x * 4 + yy; n < N_NODES; n += gridDim.x * 4) {
        float v = hnew[(long)n * D + d];
        s += v;
        s2 = fmaf(v, v, s2);
    }
    __shared__ float ls[4][D], ls2[4][D];
    ls[yy][d] = s; ls2[yy][d] = s2;
    __syncthreads();
    if (yy == 0) {
        atomicAdd(&stats[d],     ls[0][d] + ls[1][d] + ls[2][d] + ls[3][d]);
        atomicAdd(&stats[D + d], ls2[0][d] + ls2[1][d] + ls2[2][d] + ls2[3][d]);
    }
}

__global__ __launch_bounds__(256) void graph_bounds_kernel(
    const int* __restrict__ batch, int* __restrict__ start) {
    int n = blockIdx.x * 256 + threadIdx.x;
    if (n >= N_NODES) return;
    int b = batch[n];
    if (n == 0) {
        for (int g = 0; g <= b; ++g) start[g] = 0;
    } else {
        int p = batch[n - 1];
        for (int g = p + 1; g <= b; ++g) start[g] = n;
    }
    if (n == N_NODES - 1) {
        for (int g = b + 1; g <= N_GRAPHS; ++g) start[g] = N_NODES;
    }
}

// mean-pool(hnew) -> fused final-BN affine -> post FC + silu -> head
__global__ __launch_bounds__(256) void pool_head_kernel(
    const float* __restrict__ hnew, const int* __restrict__ start,
    const float* __restrict__ stats, const float* __restrict__ gamma,
    const float* __restrict__ beta,
    const float* __restrict__ pw, const float* __restrict__ pb,
    const float* __restrict__ ow, const float* __restrict__ ob,
    float* __restrict__ out) {
    int g = blockIdx.x;
    int d = threadIdx.x, yy = threadIdx.y;
    int lo = start[g], hi = start[g + 1];
    float s = 0.f;
    for (int n = lo + yy; n < hi; n += 4) s += hnew[(long)n * D + d];
    __shared__ float ls[4][D];
    ls[yy][d] = s;
    __syncthreads();
    __shared__ float grow[D];
    if (yy == 0) {
        float tot = ls[0][d] + ls[1][d] + ls[2][d] + ls[3][d];
        float gd = 0.f;
        if (hi > lo) {
            float m = tot / (float)(hi - lo);
            const float invN = 1.0f / (float)N_NODES;
            float mean = stats[d] * invN;
            float var = stats[D + d] * invN - mean * mean;
            float sc = rsqrtf(var + BN_EPS) * gamma[d];
            gd = (m - mean) * sc + beta[d];
        }
        grow[d] = gd;
    }
    __syncthreads();
    if (yy != 0) return;
    float accp = pb[d];
#pragma unroll 8
    for (int i = 0; i < D; ++i) accp = fmaf(grow[i], pw[i * D + d], accp);
    float sv = silu_f(accp) * ow[d];
    for (int off = 32; off > 0; off >>= 1) sv += __shfl_down(sv, off);
    if (d == 0) out[g] = sv + ob[0];
}

extern "C" void kernel_launch(void* const* d_in, const int* in_sizes, int n_in,
                              void* d_out, int out_size, void* d_ws, size_t ws_size,
                              hipStream_t stream) {
    const float* x        = (const float*)d_in[0];
    const int*   ei       = (const int*)d_in[1];
    const float* ea       = (const float*)d_in[2];
    const int*   batch    = (const int*)d_in[3];
    const float* pre_w    = (const float*)d_in[4];
    const float* pre_b    = (const float*)d_in[5];
    const float* Wk       = (const float*)d_in[6];
    const float* bk       = (const float*)d_in[7];
    const float* Wq       = (const float*)d_in[8];
    const float* bq       = (const float*)d_in[9];
    const float* Wv       = (const float*)d_in[10];
    const float* bv       = (const float*)d_in[11];
    const float* We       = (const float*)d_in[12];
    const float* Wskip    = (const float*)d_in[13];
    const float* conv_bias= (const float*)d_in[14];
    const float* bn_gamma = (const float*)d_in[15];
    const float* bn_beta  = (const float*)d_in[16];
    const float* post_w   = (const float*)d_in[17];
    const float* post_b   = (const float*)d_in[18];
    const float* out_w    = (const float*)d_in[19];
    const float* out_b    = (const float*)d_in[20];

    char* base = (char*)d_ws;
    float* ws = (float*)d_ws;
    const size_t NH = (size_t)N_NODES * D;
    float* bufA  = ws;
    float* bufB  = ws + NH;
    float* kb    = ws + 2 * NH;
    float* qb    = ws + 3 * NH;
    float* vb    = ws + 4 * NH;
    float* stats = ws + 5 * NH;                          // 3 * 2*D floats
    int*   start     = (int*)(stats + 6 * D);            // N_GRAPHS+1
    int*   deg       = start + (N_GRAPHS + 1);           // N_NODES
    int*   row_start = deg + N_NODES;                    // N_NODES+1
    int*   cursor    = row_start + (N_NODES + 1);        // N_NODES
    int*   partials  = cursor + N_NODES;                 // 128
    int*   csr       = partials + 128;                   // N_EDGES (tier0 only)

    size_t off_e = (size_t)((char*)(csr + N_EDGES) - base);
    off_e = (off_e + 255) & ~(size_t)255;

    // Tier 2: stride-64 ea_s + src_s + em chunk buffer
    size_t src_off2 = off_e + (size_t)N_EDGES * 64 * sizeof(float);
    size_t em_off   = (src_off2 + (size_t)N_EDGES * sizeof(int) + 255) & ~(size_t)255;
    size_t CH = 0;
    bool tier2 = false;
    if (ws_size > em_off) {
        CH = (ws_size - em_off) / (D * sizeof(float));
        if (CH > N_EDGES) CH = N_EDGES;
        tier2 = CH >= 200000;  // at most 8 chunks
    }
    // Tier 1: stride-50 ea_s + src_s (round-0 proven footprint)
    size_t src_off1 = off_e + (size_t)N_EDGES * E_IN * sizeof(float);
    bool tier1 = !tier2 && (ws_size >= src_off1 + (size_t)N_EDGES * sizeof(int));

    const int* srcIdx = ei;
    const int* dstIdx = ei + N_EDGES;

    dim3 blk(64, 4);
    const int NB_N = (N_NODES + 3) / 4;

    // CSR build
    hipMemsetAsync(deg, 0, N_NODES * sizeof(int), stream);
    hipMemsetAsync(stats, 0, 6 * D * sizeof(float), stream);
    hist_kernel<<<1024, 256, 0, stream>>>(dstIdx, deg);
    scan_sum_kernel<<<SCAN_NCH, SCAN_BLK, 0, stream>>>(deg, partials);
    scan_part_kernel<<<1, 128, 0, stream>>>(partials);
    scan_write_kernel<<<SCAN_NCH, SCAN_BLK, 0, stream>>>(deg, partials, row_start, cursor);

    float* ea2 = (float*)(base + off_e);
    int*   src2 = (int*)(base + src_off2);
    float* em  = (float*)(base + em_off);
    float* ea1 = (float*)(base + off_e);
    int*   src1 = (int*)(base + src_off1);

    if (tier2)
        scatter_perm_kernel<64><<<(N_EDGES + 3) / 4, blk, 0, stream>>>(
            srcIdx, dstIdx, ea, cursor, ea2, src2);
    else if (tier1)
        scatter_perm_kernel<E_IN><<<(N_EDGES + 3) / 4, blk, 0, stream>>>(
            srcIdx, dstIdx, ea, cursor, ea1, src1);
    else
        scatter_kernel<<<1024, 256, 0, stream>>>(dstIdx, cursor, csr);

    pre_fc_kernel<<<NB_N, blk, 0, stream>>>(x, pre_w, pre_b, bufA);

    float* hin = bufA;
    float* hout = bufB;
    for (int l = 0; l < N_LAYERS; ++l) {
        if (l == 0)
            proj_kernel<false><<<NB_N, blk, 0, stream>>>(
                hin, nullptr, nullptr, nullptr,
                Wk + l * D * D, bk + l * D, Wq + l * D * D, bq + l * D,
                Wv + l * D * D, bv + l * D, Wskip + l * D * D, conv_bias + l * D,
                kb, qb, vb, hout);
        else
            proj_kernel<true><<<NB_N, blk, 0, stream>>>(
                hin, stats + (l - 1) * 2 * D, bn_gamma + (l - 1) * D, bn_beta + (l - 1) * D,
                Wk + l * D * D, bk + l * D, Wq + l * D * D, bq + l * D,
                Wv + l * D * D, bv + l * D, Wskip + l * D * D, conv_bias + l * D,
                kb, qb, vb, hout);
        if (tier2) {
            int nch = (int)((N_EDGES + CH - 1) / CH);
            for (int c = 0; c < nch; ++c) {
                int c0 = (int)((size_t)c * CH);
                int c1 = (int)min((size_t)N_EDGES, (size_t)c0 + CH);
                edge_emb_kernel<<<(c1 - c0 + 255) / 256, 256, 0, stream>>>(
                    ea2, We + l * E_IN * D, em, c0, c1);
                gather_em_kernel<<<NB_N, blk, 0, stream>>>(
                    em, src2, row_start, kb, qb, vb, hout, c0, c1);
            }
        } else if (tier1) {
            gather_kernel<true><<<NB_N, blk, 0, stream>>>(
                ea1, src1, csr, row_start, We + l * E_IN * D, kb, qb, vb, hout);
        } else {
            gather_kernel<false><<<NB_N, blk, 0, stream>>>(
                ea, srcIdx, csr, row_start, We + l * E_IN * D, kb, qb, vb, hout);
        }
        bn_stats_kernel<<<256, blk, 0, stream>>>(hout, stats + l * 2 * D);
        float* t = hin; hin = hout; hout = t;
    }

    graph_bounds_kernel<<<(N_NODES + 255) / 256, 256, 0, stream>>>(batch, start);
    pool_head_kernel<<<N_GRAPHS, blk, 0, stream>>>(
        hin, start, stats + (N_LAYERS - 1) * 2 * D,
        bn_gamma + (N_LAYERS - 1) * D, bn_beta + (N_LAYERS - 1) * D,
        post_w, post_b, out_w, out_b, (float*)d_out);
}

// Round 3
// 3019.513 us; speedup vs baseline: 1.4484x; 1.0831x over previous
//
#include <hip/hip_runtime.h>
#include <math.h>

#define N_NODES 100000
#define N_EDGES 1600000
#define F_IN 92
#define E_IN 50
#define D 64
#define N_LAYERS 3
#define N_GRAPHS 512
#define BN_EPS 1e-5f

#define SCAN_BLK 1024
#define SCAN_NCH ((N_NODES + SCAN_BLK - 1) / SCAN_BLK)  // 98

__device__ __forceinline__ float silu_f(float x) {
    return x / (1.0f + __expf(-x));
}

__device__ __forceinline__ float bcast_f(float v, int lane) {
    return __int_as_float(__builtin_amdgcn_readlane(__float_as_int(v), lane));
}

// ---------------- CSR build ----------------
__global__ __launch_bounds__(256) void hist_kernel(
    const int* __restrict__ dst, int* __restrict__ deg) {
    for (int e = blockIdx.x * 256 + threadIdx.x; e < N_EDGES; e += gridDim.x * 256)
        atomicAdd(&deg[dst[e]], 1);
}

// 3-phase multi-block exclusive scan
__global__ __launch_bounds__(SCAN_BLK) void scan_sum_kernel(
    const int* __restrict__ deg, int* __restrict__ partials) {
    int b = blockIdx.x, t = threadIdx.x;
    int i = b * SCAN_BLK + t;
    int v = (i < N_NODES) ? deg[i] : 0;
    __shared__ int wsum[16];
    for (int off = 32; off > 0; off >>= 1) v += __shfl_down(v, off);
    if ((t & 63) == 0) wsum[t >> 6] = v;
    __syncthreads();
    if (t < 16) {
        int s = wsum[t];
        for (int off = 8; off > 0; off >>= 1) s += __shfl_down(s, off);
        if (t == 0) partials[b] = s;
    }
}

__global__ __launch_bounds__(128) void scan_part_kernel(int* __restrict__ partials) {
    int t = threadIdx.x;
    __shared__ int sh[128];
    sh[t] = (t < SCAN_NCH) ? partials[t] : 0;
    __syncthreads();
    for (int off = 1; off < 128; off <<= 1) {
        int v = (t >= off) ? sh[t - off] : 0;
        __syncthreads();
        sh[t] += v;
        __syncthreads();
    }
    if (t < SCAN_NCH) partials[t] = (t == 0) ? 0 : sh[t - 1];  // exclusive
}

__global__ __launch_bounds__(SCAN_BLK) void scan_write_kernel(
    const int* __restrict__ deg, const int* __restrict__ partials,
    int* __restrict__ row_start, int* __restrict__ cursor) {
    int b = blockIdx.x, t = threadIdx.x;
    int i = b * SCAN_BLK + t;
    int v = (i < N_NODES) ? deg[i] : 0;
    __shared__ int sh[SCAN_BLK];
    sh[t] = v;
    __syncthreads();
    for (int off = 1; off < SCAN_BLK; off <<= 1) {
        int x = (t >= off) ? sh[t - off] : 0;
        __syncthreads();
        sh[t] += x;
        __syncthreads();
    }
    int excl = partials[b] + sh[t] - v;
    if (i < N_NODES) { row_start[i] = excl; cursor[i] = excl; }
    if (i == N_NODES - 1) row_start[N_NODES] = excl + v;
}

// fallback path (no workspace for permuted edges): plain csr scatter
__global__ __launch_bounds__(256) void scatter_kernel(
    const int* __restrict__ dst, int* __restrict__ cursor,
    int* __restrict__ csr) {
    for (int e = blockIdx.x * 256 + threadIdx.x; e < N_EDGES; e += gridDim.x * 256) {
        int pos = atomicAdd(&cursor[dst[e]], 1);
        csr[pos] = e;
    }
}

// tier1 fallback: fused scatter+permute at stride E_IN (round-0 proven)
template <int STRIDE>
__global__ __launch_bounds__(256) void scatter_perm_kernel(
    const int* __restrict__ srcIdx, const int* __restrict__ dstIdx,
    const float* __restrict__ ea, int* __restrict__ cursor,
    float* __restrict__ ea_s, int* __restrict__ src_s) {
    int d = threadIdx.x;
    int e = blockIdx.x * 4 + threadIdx.y;
    if (e >= N_EDGES) return;
    int pos = 0;
    if (d == 0) pos = atomicAdd(&cursor[dstIdx[e]], 1);
    pos = __builtin_amdgcn_readlane(pos, 0);
    if (d == 0) src_s[pos] = srcIdx[e];
    if (d < E_IN) ea_s[(long)pos * STRIDE + d] = ea[(long)e * E_IN + d];
}

// Tier2 permutation, pass 1: atomics only. Sequential reads of dst/src,
// sequential write of pos_arr; src_s scatter is 4B -> coalesces in L2.
// Decouples the atomic round-trip from the bulk data copy.
__global__ __launch_bounds__(256) void pos_kernel(
    const int* __restrict__ srcIdx, const int* __restrict__ dstIdx,
    int* __restrict__ cursor, int* __restrict__ pos_arr,
    int* __restrict__ src_s) {
    for (int e = blockIdx.x * 256 + threadIdx.x; e < N_EDGES; e += gridDim.x * 256) {
        int p = atomicAdd(&cursor[dstIdx[e]], 1);
        pos_arr[e] = p;
        src_s[p] = srcIdx[e];
    }
}

// Tier2 permutation, pass 2: pure data movement. One wave owns 64 edges:
// preload 64 positions coalesced, then stream rows. Sequential 200B loads
// (distance-1 prefetch) + random FULL-256B stores (lanes 50..63 pad 0),
// so no partial-line RMW and stores are fire-and-forget (no atomic dep).
__global__ __launch_bounds__(256) void copy_rows_kernel(
    const float* __restrict__ ea, const int* __restrict__ pos_arr,
    float* __restrict__ ea_s) {
    int d = threadIdx.x;
    long ebase = ((long)blockIdx.x * 4 + threadIdx.y) * 64;
    if (ebase >= N_EDGES) return;
    int cnt = (int)min((long)64, (long)N_EDGES - ebase);
    int p_l = (d < cnt) ? pos_arr[ebase + d] : 0;
    float r_c = (d < E_IN) ? ea[ebase * E_IN + d] : 0.f;
    for (int j = 0; j < cnt; ++j) {
        float r_n = 0.f;
        if (d < E_IN && j + 1 < cnt) r_n = ea[(ebase + j + 1) * E_IN + d];
        int p = __builtin_amdgcn_readlane(p_l, j);
        ea_s[(long)p * 64 + d] = r_c;  // lanes >= E_IN write 0 pad (full line)
        r_c = r_n;
    }
}

// ---------------- dense stages ----------------
// h = silu(x @ pre_w + pre_b)
__global__ __launch_bounds__(256) void pre_fc_kernel(
    const float* __restrict__ x, const float* __restrict__ w,
    const float* __restrict__ b, float* __restrict__ h) {
    __shared__ float xs[4][F_IN];
    int d = threadIdx.x, yy = threadIdx.y;
    int node = blockIdx.x * 4 + yy;
    if (node < N_NODES) {
        const float* xrow = x + (long)node * F_IN;
        for (int i = d; i < F_IN; i += 64) xs[yy][i] = xrow[i];
    }
    __syncthreads();
    if (node >= N_NODES) return;
    float acc = b[d];
#pragma unroll 4
    for (int i = 0; i < F_IN; ++i) acc = fmaf(xs[yy][i], w[i * D + d], acc);
    h[(long)node * D + d] = silu_f(acc);
}

// Optional-BN-normalize input, then 4 fused GEMMs: k,q,v + skip(hnew=h@Ws+bias)
template <bool BN>
__global__ __launch_bounds__(256) void proj_kernel(
    const float* __restrict__ hin, const float* __restrict__ stats,
    const float* __restrict__ gamma, const float* __restrict__ beta,
    const float* __restrict__ Wk, const float* __restrict__ bk,
    const float* __restrict__ Wq, const float* __restrict__ bq,
    const float* __restrict__ Wv, const float* __restrict__ bv,
    const float* __restrict__ Ws, const float* __restrict__ cbias,
    float* __restrict__ ko, float* __restrict__ qo, float* __restrict__ vo,
    float* __restrict__ hnew) {
    __shared__ float hs[4][D];
    int d = threadIdx.x, yy = threadIdx.y;
    int node = blockIdx.x * 4 + yy;
    if (node < N_NODES) {
        float xv = hin[(long)node * D + d];
        if (BN) {
            const float invN = 1.0f / (float)N_NODES;
            float mean = stats[d] * invN;
            float var = stats[D + d] * invN - mean * mean;
            float sc = rsqrtf(var + BN_EPS) * gamma[d];
            xv = (xv - mean) * sc + beta[d];
        }
        hs[yy][d] = xv;
    }
    __syncthreads();
    if (node >= N_NODES) return;
    float ak = bk[d], aq = bq[d], av = bv[d], as = cbias[d];
#pragma unroll 8
    for (int i = 0; i < D; ++i) {
        float hv = hs[yy][i];
        ak = fmaf(hv, Wk[i * D + d], ak);
        aq = fmaf(hv, Wq[i * D + d], aq);
        av = fmaf(hv, Wv[i * D + d], av);
        as = fmaf(hv, Ws[i * D + d], as);
    }
    long off = (long)node * D + d;
    ko[off] = ak; qo[off] = aq; vo[off] = av; hnew[off] = as;
}

// Edge-embedding GEMM: em[p-c0][d] = sum_i ea_s[p][i] * We[i][d], p in [c0,c1).
// Lane owns one edge: 64 accumulators in VGPRs, We via SGPR broadcast loads.
__global__ __launch_bounds__(256) void edge_emb_kernel(
    const float* __restrict__ ea_s, const float* __restrict__ We,
    float* __restrict__ em, int c0, int c1) {
    int p = c0 + blockIdx.x * 256 + threadIdx.x;
    if (p >= c1) return;
    const float* row = ea_s + (long)p * 64;  // 256B-aligned rows (stride 64)
    float acc[D];
#pragma unroll
    for (int d = 0; d < D; ++d) acc[d] = 0.f;
#pragma unroll
    for (int i = 0; i < E_IN; i += 2) {
        float2 ev = *reinterpret_cast<const float2*>(row + i);
#pragma unroll
        for (int d = 0; d < D; ++d) acc[d] = fmaf(ev.x, We[i * D + d], acc[d]);
#pragma unroll
        for (int d = 0; d < D; ++d) acc[d] = fmaf(ev.y, We[(i + 1) * D + d], acc[d]);
    }
    float* out = em + (long)(p - c0) * D;
#pragma unroll
    for (int d = 0; d < D; d += 4)
        *reinterpret_cast<float4*>(out + d) =
            make_float4(acc[d], acc[d + 1], acc[d + 2], acc[d + 3]);
}

// Gather with precomputed edge embedding: per edge 3 coalesced row loads
// (em sequential; q,v gathered). Distance-2 software pipeline: loads for
// edge j+2 issue while edge j computes -> ~2 iterations of latency slack.
__global__ __launch_bounds__(256) void gather_em_kernel(
    const float* __restrict__ em, const int* __restrict__ src_s,
    const int* __restrict__ row_start,
    const float* __restrict__ kb, const float* __restrict__ qb,
    const float* __restrict__ vb, float* __restrict__ hnew,
    int c0, int c1) {
    int d = threadIdx.x;
    int node = blockIdx.x * 4 + threadIdx.y;
    if (node >= N_NODES) return;
    int lo = row_start[node], hi = row_start[node + 1];
    lo = max(lo, c0); hi = min(hi, c1);
    if (lo >= hi) return;
    float kv = kb[(long)node * D + d];
    float acc = 0.f;
    for (int base = lo; base < hi; base += 64) {
        int cnt = min(hi - base, 64);
        int s_l = 0;
        if (d < cnt) s_l = src_s[base + d];
        int s0 = __builtin_amdgcn_readlane(s_l, 0);
        float q_c = qb[(long)s0 * D + d];
        float v_c = vb[(long)s0 * D + d];
        float e_c = em[(long)(base - c0) * D + d];
        float q_n = 0.f, v_n = 0.f, e_n = 0.f;
        if (cnt > 1) {
            int s1 = __builtin_amdgcn_readlane(s_l, 1);
            q_n = qb[(long)s1 * D + d];
            v_n = vb[(long)s1 * D + d];
            e_n = em[(long)(base + 1 - c0) * D + d];
        }
        for (int j = 0; j < cnt; ++j) {
            float q_2 = 0.f, v_2 = 0.f, e_2 = 0.f;
            if (j + 2 < cnt) {
                int s2 = __builtin_amdgcn_readlane(s_l, j + 2);
                q_2 = qb[(long)s2 * D + d];
                v_2 = vb[(long)s2 * D + d];
                e_2 = em[(long)(base + j + 2 - c0) * D + d];
            }
            float gate = silu_f(kv + q_c + 2.0f * e_c);
            acc = fmaf(gate, v_c + e_c, acc);
            q_c = q_n; v_c = v_n; e_c = e_n;
            q_n = q_2; v_n = v_2; e_n = e_2;
        }
    }
    long off = (long)node * D + d;
    hnew[off] += acc;
}

// Legacy one-wave-per-node gather (fallback tiers).
template <bool PERM>
__global__ __launch_bounds__(256) void gather_kernel(
    const float* __restrict__ ea, const int* __restrict__ srcArr,
    const int* __restrict__ csr, const int* __restrict__ row_start,
    const float* __restrict__ We,
    const float* __restrict__ kb, const float* __restrict__ qb,
    const float* __restrict__ vb, float* __restrict__ hnew) {
    int d = threadIdx.x;
    int node = blockIdx.x * 4 + threadIdx.y;
    if (node >= N_NODES) return;
    float WeReg[E_IN];
#pragma unroll
    for (int i = 0; i < E_IN; ++i) WeReg[i] = We[i * D + d];
    int lo = row_start[node], hi = row_start[node + 1];
    float kv = kb[(long)node * D + d];
    float acc = 0.f;
    for (int base = lo; base < hi; base += 64) {
        int cnt = min(hi - base, 64);
        int e_l = 0, s_l = 0;
        if (d < cnt) {
            int p = base + d;
            e_l = PERM ? p : csr[p];
            s_l = PERM ? srcArr[p] : srcArr[e_l];
        }
        int s_c = __builtin_amdgcn_readlane(s_l, 0);
        int r_c = PERM ? base : __builtin_amdgcn_readlane(e_l, 0);
        float q_c = qb[(long)s_c * D + d];
        float v_c = vb[(long)s_c * D + d];
        float e_c = (d < E_IN) ? ea[(long)r_c * E_IN + d] : 0.f;
        for (int j = 0; j < cnt; ++j) {
            float q_n = 0.f, v_n = 0.f, e_n = 0.f;
            if (j + 1 < cnt) {
                int s_n = __builtin_amdgcn_readlane(s_l, j + 1);
                int r_n = PERM ? (base + j + 1) : __builtin_amdgcn_readlane(e_l, j + 1);
                q_n = qb[(long)s_n * D + d];
                v_n = vb[(long)s_n * D + d];
                e_n = (d < E_IN) ? ea[(long)r_n * E_IN + d] : 0.f;
            }
            float ed0 = 0.f, ed1 = 0.f;
#pragma unroll
            for (int i = 0; i < E_IN; i += 2) {
                ed0 = fmaf(bcast_f(e_c, i), WeReg[i], ed0);
                ed1 = fmaf(bcast_f(e_c, i + 1), WeReg[i + 1], ed1);
            }
            float ed = ed0 + ed1;
            float gate = silu_f(kv + q_c + 2.0f * ed);
            acc = fmaf(gate, v_c + ed, acc);
            q_c = q_n; v_c = v_n; e_c = e_n;
        }
    }
    long off = (long)node * D + d;
    hnew[off] += acc;
}

// per-column sum & sumsq
__global__ __launch_bounds__(256) void bn_stats_kernel(
    const float* __restrict__ hnew, float* __restrict__ stats) {
    int d = threadIdx.x, yy = threadIdx.y;
    float s = 0.f, s2 = 0.f;
    for (int n = blockIdx.x * 4 + yy; n < N_NODES; n += gridDim.x * 4) {
        float v = hnew[(long)n * D + d];
        s += v;
        s2 = fmaf(v, v, s2);
    }
    __shared__ float ls[4][D], ls2[4][D];
    ls[yy][d] = s; ls2[yy][d] = s2;
    __syncthreads();
    if (yy == 0) {
        atomicAdd(&stats[d],     ls[0][d] + ls[1][d] + ls[2][d] + ls[3][d]);
        atomicAdd(&stats[D + d], ls2[0][d] + ls2[1][d] + ls2[2][d] + ls2[3][d]);
    }
}

__global__ __launch_bounds__(256) void graph_bounds_kernel(
    const int* __restrict__ batch, int* __restrict__ start) {
    int n = blockIdx.x * 256 + threadIdx.x;
    if (n >= N_NODES) return;
    int b = batch[n];
    if (n == 0) {
        for (int g = 0; g <= b; ++g) start[g] = 0;
    } else {
        int p = batch[n - 1];
        for (int g = p + 1; g <= b; ++g) start[g] = n;
    }
    if (n == N_NODES - 1) {
        for (int g = b + 1; g <= N_GRAPHS; ++g) start[g] = N_NODES;
    }
}

// mean-pool(hnew) -> fused final-BN affine -> post FC + silu -> head
__global__ __launch_bounds__(256) void pool_head_kernel(
    const float* __restrict__ hnew, const int* __restrict__ start,
    const float* __restrict__ stats, const float* __restrict__ gamma,
    const float* __restrict__ beta,
    const float* __restrict__ pw, const float* __restrict__ pb,
    const float* __restrict__ ow, const float* __restrict__ ob,
    float* __restrict__ out) {
    int g = blockIdx.x;
    int d = threadIdx.x, yy = threadIdx.y;
    int lo = start[g], hi = start[g + 1];
    float s = 0.f;
    for (int n = lo + yy; n < hi; n += 4) s += hnew[(long)n * D + d];
    __shared__ float ls[4][D];
    ls[yy][d] = s;
    __syncthreads();
    __shared__ float grow[D];
    if (yy == 0) {
        float tot = ls[0][d] + ls[1][d] + ls[2][d] + ls[3][d];
        float gd = 0.f;
        if (hi > lo) {
            float m = tot / (float)(hi - lo);
            const float invN = 1.0f / (float)N_NODES;
            float mean = stats[d] * invN;
            float var = stats[D + d] * invN - mean * mean;
            float sc = rsqrtf(var + BN_EPS) * gamma[d];
            gd = (m - mean) * sc + beta[d];
        }
        grow[d] = gd;
    }
    __syncthreads();
    if (yy != 0) return;
    float accp = pb[d];
#pragma unroll 8
    for (int i = 0; i < D; ++i) accp = fmaf(grow[i], pw[i * D + d], accp);
    float sv = silu_f(accp) * ow[d];
    for (int off = 32; off > 0; off >>= 1) sv += __shfl_down(sv, off);
    if (d == 0) out[g] = sv + ob[0];
}

extern "C" void kernel_launch(void* const* d_in, const int* in_sizes, int n_in,
                              void* d_out, int out_size, void* d_ws, size_t ws_size,
                              hipStream_t stream) {
    const float* x        = (const float*)d_in[0];
    const int*   ei       = (const int*)d_in[1];
    const float* ea       = (const float*)d_in[2];
    const int*   batch    = (const int*)d_in[3];
    const float* pre_w    = (const float*)d_in[4];
    const float* pre_b    = (const float*)d_in[5];
    const float* Wk       = (const float*)d_in[6];
    const float* bk       = (const float*)d_in[7];
    const float* Wq       = (const float*)d_in[8];
    const float* bq       = (const float*)d_in[9];
    const float* Wv       = (const float*)d_in[10];
    const float* bv       = (const float*)d_in[11];
    const float* We       = (const float*)d_in[12];
    const float* Wskip    = (const float*)d_in[13];
    const float* conv_bias= (const float*)d_in[14];
    const float* bn_gamma = (const float*)d_in[15];
    const float* bn_beta  = (const float*)d_in[16];
    const float* post_w   = (const float*)d_in[17];
    const float* post_b   = (const float*)d_in[18];
    const float* out_w    = (const float*)d_in[19];
    const float* out_b    = (const float*)d_in[20];

    char* base = (char*)d_ws;
    float* ws = (float*)d_ws;
    const size_t NH = (size_t)N_NODES * D;
    float* bufA  = ws;
    float* bufB  = ws + NH;
    float* kb    = ws + 2 * NH;
    float* qb    = ws + 3 * NH;
    float* vb    = ws + 4 * NH;
    float* stats = ws + 5 * NH;                          // 3 * 2*D floats
    int*   start     = (int*)(stats + 6 * D);            // N_GRAPHS+1
    int*   deg       = start + (N_GRAPHS + 1);           // N_NODES
    int*   row_start = deg + N_NODES;                    // N_NODES+1
    int*   cursor    = row_start + (N_NODES + 1);        // N_NODES
    int*   partials  = cursor + N_NODES;                 // 128
    int*   csr       = partials + 128;                   // N_EDGES (csr / pos_arr)

    size_t off_e = (size_t)((char*)(csr + N_EDGES) - base);
    off_e = (off_e + 255) & ~(size_t)255;

    // Tier 2: stride-64 ea_s + src_s + em chunk buffer
    size_t src_off2 = off_e + (size_t)N_EDGES * 64 * sizeof(float);
    size_t em_off   = (src_off2 + (size_t)N_EDGES * sizeof(int) + 255) & ~(size_t)255;
    size_t CH = 0;
    bool tier2 = false;
    if (ws_size > em_off) {
        CH = (ws_size - em_off) / (D * sizeof(float));
        if (CH > N_EDGES) CH = N_EDGES;
        tier2 = CH >= 200000;  // at most 8 chunks
    }
    // Tier 1: stride-50 ea_s + src_s (round-0 proven footprint)
    size_t src_off1 = off_e + (size_t)N_EDGES * E_IN * sizeof(float);
    bool tier1 = !tier2 && (ws_size >= src_off1 + (size_t)N_EDGES * sizeof(int));

    const int* srcIdx = ei;
    const int* dstIdx = ei + N_EDGES;

    dim3 blk(64, 4);
    const int NB_N = (N_NODES + 3) / 4;

    // CSR build
    hipMemsetAsync(deg, 0, N_NODES * sizeof(int), stream);
    hipMemsetAsync(stats, 0, 6 * D * sizeof(float), stream);
    hist_kernel<<<1024, 256, 0, stream>>>(dstIdx, deg);
    scan_sum_kernel<<<SCAN_NCH, SCAN_BLK, 0, stream>>>(deg, partials);
    scan_part_kernel<<<1, 128, 0, stream>>>(partials);
    scan_write_kernel<<<SCAN_NCH, SCAN_BLK, 0, stream>>>(deg, partials, row_start, cursor);

    float* ea2 = (float*)(base + off_e);
    int*   src2 = (int*)(base + src_off2);
    float* em  = (float*)(base + em_off);
    float* ea1 = (float*)(base + off_e);
    int*   src1 = (int*)(base + src_off1);

    if (tier2) {
        // pass 1: atomics only (pos_arr reuses the csr region)
        pos_kernel<<<1024, 256, 0, stream>>>(srcIdx, dstIdx, cursor, csr, src2);
        // pass 2: pure copy, padded full-line stores
        copy_rows_kernel<<<(N_EDGES + 255) / 256, blk, 0, stream>>>(ea, csr, ea2);
    } else if (tier1) {
        scatter_perm_kernel<E_IN><<<(N_EDGES + 3) / 4, blk, 0, stream>>>(
            srcIdx, dstIdx, ea, cursor, ea1, src1);
    } else {
        scatter_kernel<<<1024, 256, 0, stream>>>(dstIdx, cursor, csr);
    }

    pre_fc_kernel<<<NB_N, blk, 0, stream>>>(x, pre_w, pre_b, bufA);

    float* hin = bufA;
    float* hout = bufB;
    for (int l = 0; l < N_LAYERS; ++l) {
        if (l == 0)
            proj_kernel<false><<<NB_N, blk, 0, stream>>>(
                hin, nullptr, nullptr, nullptr,
                Wk + l * D * D, bk + l * D, Wq + l * D * D, bq + l * D,
                Wv + l * D * D, bv + l * D, Wskip + l * D * D, conv_bias + l * D,
                kb, qb, vb, hout);
        else
            proj_kernel<true><<<NB_N, blk, 0, stream>>>(
                hin, stats + (l - 1) * 2 * D, bn_gamma + (l - 1) * D, bn_beta + (l - 1) * D,
                Wk + l * D * D, bk + l * D, Wq + l * D * D, bq + l * D,
                Wv + l * D * D, bv + l * D, Wskip + l * D * D, conv_bias + l * D,
                kb, qb, vb, hout);
        if (tier2) {
            int nch = (int)((N_EDGES + CH - 1) / CH);
            for (int c = 0; c < nch; ++c) {
                int c0 = (int)((size_t)c * CH);
                int c1 = (int)min((size_t)N_EDGES, (size_t)c0 + CH);
                edge_emb_kernel<<<(c1 - c0 + 255) / 256, 256, 0, stream>>>(
                    ea2, We + l * E_IN * D, em, c0, c1);
                gather_em_kernel<<<NB_N, blk, 0, stream>>>(
                    em, src2, row_start, kb, qb, vb, hout, c0, c1);
            }
        } else if (tier1) {
            gather_kernel<true><<<NB_N, blk, 0, stream>>>(
                ea1, src1, csr, row_start, We + l * E_IN * D, kb, qb, vb, hout);
        } else {
            gather_kernel<false><<<NB_N, blk, 0, stream>>>(
                ea, srcIdx, csr, row_start, We + l * E_IN * D, kb, qb, vb, hout);
        }
        bn_stats_kernel<<<256, blk, 0, stream>>>(hout, stats + l * 2 * D);
        float* t = hin; hin = hout; hout = t;
    }

    graph_bounds_kernel<<<(N_NODES + 255) / 256, 256, 0, stream>>>(batch, start);
    pool_head_kernel<<<N_GRAPHS, blk, 0, stream>>>(
        hin, start, stats + (N_LAYERS - 1) * 2 * D,
        bn_gamma + (N_LAYERS - 1) * D, bn_beta + (N_LAYERS - 1) * D,
        post_w, post_b, out_w, out_b, (float*)d_out);
}

// Round 5
// 2501.044 us; speedup vs baseline: 1.7486x; 1.2073x over previous
//
#include <hip/hip_runtime.h>
#include <math.h>

#define N_NODES 100000
#define N_EDGES 1600000
#define F_IN 92
#define E_IN 50
#define D 64
#define N_LAYERS 3
#define N_GRAPHS 512
#define BN_EPS 1e-5f

#define SCAN_BLK 1024
#define SCAN_NCH ((N_NODES + SCAN_BLK - 1) / SCAN_BLK)  // 98
#define EMB_TILE 256                                     // edges per block (N_EDGES % 256 == 0)

__device__ __forceinline__ float silu_f(float x) {
    return x / (1.0f + __expf(-x));
}

__device__ __forceinline__ float bcast_f(float v, int lane) {
    return __int_as_float(__builtin_amdgcn_readlane(__float_as_int(v), lane));
}

// ---------------- permutation build ----------------
// Pass A (replaces hist): deg histogram AND per-edge within-node rank in one
// atomic pass. within lands in pos_arr (finalized by pos_fin / overwritten by
// fallback scatter -- both fully rewrite the region).
__global__ __launch_bounds__(256) void deg_within_kernel(
    const int* __restrict__ dst, int* __restrict__ deg, int* __restrict__ within) {
    for (int e = blockIdx.x * 256 + threadIdx.x; e < N_EDGES; e += gridDim.x * 256)
        within[e] = atomicAdd(&deg[dst[e]], 1);
}

// 3-phase multi-block exclusive scan
__global__ __launch_bounds__(SCAN_BLK) void scan_sum_kernel(
    const int* __restrict__ deg, int* __restrict__ partials) {
    int b = blockIdx.x, t = threadIdx.x;
    int i = b * SCAN_BLK + t;
    int v = (i < N_NODES) ? deg[i] : 0;
    __shared__ int wsum[16];
    for (int off = 32; off > 0; off >>= 1) v += __shfl_down(v, off);
    if ((t & 63) == 0) wsum[t >> 6] = v;
    __syncthreads();
    if (t < 16) {
        int s = wsum[t];
        for (int off = 8; off > 0; off >>= 1) s += __shfl_down(s, off);
        if (t == 0) partials[b] = s;
    }
}

__global__ __launch_bounds__(128) void scan_part_kernel(int* __restrict__ partials) {
    int t = threadIdx.x;
    __shared__ int sh[128];
    sh[t] = (t < SCAN_NCH) ? partials[t] : 0;
    __syncthreads();
    for (int off = 1; off < 128; off <<= 1) {
        int v = (t >= off) ? sh[t - off] : 0;
        __syncthreads();
        sh[t] += v;
        __syncthreads();
    }
    if (t < SCAN_NCH) partials[t] = (t == 0) ? 0 : sh[t - 1];  // exclusive
}

__global__ __launch_bounds__(SCAN_BLK) void scan_write_kernel(
    const int* __restrict__ deg, const int* __restrict__ partials,
    int* __restrict__ row_start, int* __restrict__ cursor) {
    int b = blockIdx.x, t = threadIdx.x;
    int i = b * SCAN_BLK + t;
    int v = (i < N_NODES) ? deg[i] : 0;
    __shared__ int sh[SCAN_BLK];
    sh[t] = v;
    __syncthreads();
    for (int off = 1; off < SCAN_BLK; off <<= 1) {
        int x = (t >= off) ? sh[t - off] : 0;
        __syncthreads();
        sh[t] += x;
        __syncthreads();
    }
    int excl = partials[b] + sh[t] - v;
    if (i < N_NODES) { row_start[i] = excl; cursor[i] = excl; }
    if (i == N_NODES - 1) row_start[N_NODES] = excl + v;
}

// Pass B: finalize pos (sequential reads; row_start gather is L2-resident 400KB)
// and scatter src into dst-sorted order (4B scatter, coalesces in L2).
__global__ __launch_bounds__(256) void pos_fin_kernel(
    const int* __restrict__ srcIdx, const int* __restrict__ dst,
    const int* __restrict__ row_start, int* __restrict__ pos_arr,
    int* __restrict__ src_s) {
    for (int e = blockIdx.x * 256 + threadIdx.x; e < N_EDGES; e += gridDim.x * 256) {
        int p = row_start[dst[e]] + pos_arr[e];  // pos_arr held within-rank
        pos_arr[e] = p;
        src_s[p] = srcIdx[e];
    }
}

// fallback tier0: plain csr scatter (overwrites every slot of the within region)
__global__ __launch_bounds__(256) void scatter_kernel(
    const int* __restrict__ dst, int* __restrict__ cursor,
    int* __restrict__ csr) {
    for (int e = blockIdx.x * 256 + threadIdx.x; e < N_EDGES; e += gridDim.x * 256) {
        int pos = atomicAdd(&cursor[dst[e]], 1);
        csr[pos] = e;
    }
}

// fallback tier1: fused scatter+permute at stride E_IN (round-0 proven)
template <int STRIDE>
__global__ __launch_bounds__(256) void scatter_perm_kernel(
    const int* __restrict__ srcIdx, const int* __restrict__ dstIdx,
    const float* __restrict__ ea, int* __restrict__ cursor,
    float* __restrict__ ea_s, int* __restrict__ src_s) {
    int d = threadIdx.x;
    int e = blockIdx.x * 4 + threadIdx.y;
    if (e >= N_EDGES) return;
    int pos = 0;
    if (d == 0) pos = atomicAdd(&cursor[dstIdx[e]], 1);
    pos = __builtin_amdgcn_readlane(pos, 0);
    if (d == 0) src_s[pos] = srcIdx[e];
    if (d < E_IN) ea_s[(long)pos * STRIDE + d] = ea[(long)e * E_IN + d];
}

// ---------------- dense stages ----------------
// h = silu(x @ pre_w + pre_b)
__global__ __launch_bounds__(256) void pre_fc_kernel(
    const float* __restrict__ x, const float* __restrict__ w,
    const float* __restrict__ b, float* __restrict__ h) {
    __shared__ float xs[4][F_IN];
    int d = threadIdx.x, yy = threadIdx.y;
    int node = blockIdx.x * 4 + yy;
    if (node < N_NODES) {
        const float* xrow = x + (long)node * F_IN;
        for (int i = d; i < F_IN; i += 64) xs[yy][i] = xrow[i];
    }
    __syncthreads();
    if (node >= N_NODES) return;
    float acc = b[d];
#pragma unroll 4
    for (int i = 0; i < F_IN; ++i) acc = fmaf(xs[yy][i], w[i * D + d], acc);
    h[(long)node * D + d] = silu_f(acc);
}

// Optional-BN-normalize input, then 4 fused GEMMs: k,q,v + skip(hnew=h@Ws+bias)
template <bool BN>
__global__ __launch_bounds__(256) void proj_kernel(
    const float* __restrict__ hin, const float* __restrict__ stats,
    const float* __restrict__ gamma, const float* __restrict__ beta,
    const float* __restrict__ Wk, const float* __restrict__ bk,
    const float* __restrict__ Wq, const float* __restrict__ bq,
    const float* __restrict__ Wv, const float* __restrict__ bv,
    const float* __restrict__ Ws, const float* __restrict__ cbias,
    float* __restrict__ ko, float* __restrict__ qo, float* __restrict__ vo,
    float* __restrict__ hnew) {
    __shared__ float hs[4][D];
    int d = threadIdx.x, yy = threadIdx.y;
    int node = blockIdx.x * 4 + yy;
    if (node < N_NODES) {
        float xv = hin[(long)node * D + d];
        if (BN) {
            const float invN = 1.0f / (float)N_NODES;
            float mean = stats[d] * invN;
            float var = stats[D + d] * invN - mean * mean;
            float sc = rsqrtf(var + BN_EPS) * gamma[d];
            xv = (xv - mean) * sc + beta[d];
        }
        hs[yy][d] = xv;
    }
    __syncthreads();
    if (node >= N_NODES) return;
    float ak = bk[d], aq = bq[d], av = bv[d], as = cbias[d];
#pragma unroll 8
    for (int i = 0; i < D; ++i) {
        float hv = hs[yy][i];
        ak = fmaf(hv, Wk[i * D + d], ak);
        aq = fmaf(hv, Wq[i * D + d], aq);
        av = fmaf(hv, Wv[i * D + d], av);
        as = fmaf(hv, Ws[i * D + d], as);
    }
    long off = (long)node * D + d;
    ko[off] = ak; qo[off] = aq; vo[off] = av; hnew[off] = as;
}

// Fused edge-embedding GEMM + permutation. Grid walks edges in ORIGINAL order:
//  - cooperative coalesced load of the contiguous 256x50f ea tile into LDS
//    (fixes the 1.77x fetch inflation: compiler d-blocking re-reads LDS, not HBM)
//  - thread-per-edge GEMM against We via uniform s_load broadcast
//  - scatter the 256B em row to its dst-sorted slot pos (random full-line
//    write, fire-and-forget; proven fast by round-3 copy_rows)
// Eliminates ea_s and the separate copy pass entirely.
__global__ __launch_bounds__(256) void edge_emb_perm_kernel(
    const float* __restrict__ ea, const int* __restrict__ pos_arr,
    const float* __restrict__ We, float* __restrict__ em) {
    __shared__ float tile[EMB_TILE * E_IN];  // 51200 B
    int t = threadIdx.x;
    long e0 = (long)blockIdx.x * EMB_TILE;
    const float2* g = (const float2*)(ea + e0 * E_IN);  // 51200B-aligned tile
    float2* l2 = (float2*)tile;
#pragma unroll
    for (int k = 0; k < (EMB_TILE * E_IN) / 2; k += 256)
        l2[k + t] = g[k + t];
    int pos = pos_arr[e0 + t];
    __syncthreads();
    const float* row = tile + t * E_IN;
    float acc[D];
#pragma unroll
    for (int d = 0; d < D; ++d) acc[d] = 0.f;
#pragma unroll 5
    for (int i = 0; i < E_IN; ++i) {
        float ev = row[i];
#pragma unroll
        for (int d = 0; d < D; ++d) acc[d] = fmaf(ev, We[i * D + d], acc[d]);
    }
    float* out = em + (long)pos * D;
#pragma unroll
    for (int d = 0; d < D; d += 4)
        *reinterpret_cast<float4*>(out + d) =
            make_float4(acc[d], acc[d + 1], acc[d + 2], acc[d + 3]);
}

// Gather with precomputed (dst-sorted) edge embedding: per edge 3 coalesced
// row loads (em sequential; q,v gathered). Distance-2 software pipeline.
__global__ __launch_bounds__(256) void gather_em_kernel(
    const float* __restrict__ em, const int* __restrict__ src_s,
    const int* __restrict__ row_start,
    const float* __restrict__ kb, const float* __restrict__ qb,
    const float* __restrict__ vb, float* __restrict__ hnew) {
    int d = threadIdx.x;
    int node = blockIdx.x * 4 + threadIdx.y;
    if (node >= N_NODES) return;
    int lo = row_start[node], hi = row_start[node + 1];
    if (lo >= hi) return;
    float kv = kb[(long)node * D + d];
    float acc = 0.f;
    for (int base = lo; base < hi; base += 64) {
        int cnt = min(hi - base, 64);
        int s_l = 0;
        if (d < cnt) s_l = src_s[base + d];
        int s0 = __builtin_amdgcn_readlane(s_l, 0);
        float q_c = qb[(long)s0 * D + d];
        float v_c = vb[(long)s0 * D + d];
        float e_c = em[(long)base * D + d];
        float q_n = 0.f, v_n = 0.f, e_n = 0.f;
        if (cnt > 1) {
            int s1 = __builtin_amdgcn_readlane(s_l, 1);
            q_n = qb[(long)s1 * D + d];
            v_n = vb[(long)s1 * D + d];
            e_n = em[(long)(base + 1) * D + d];
        }
        for (int j = 0; j < cnt; ++j) {
            float q_2 = 0.f, v_2 = 0.f, e_2 = 0.f;
            if (j + 2 < cnt) {
                int s2 = __builtin_amdgcn_readlane(s_l, j + 2);
                q_2 = qb[(long)s2 * D + d];
                v_2 = vb[(long)s2 * D + d];
                e_2 = em[(long)(base + j + 2) * D + d];
            }
            float gate = silu_f(kv + q_c + 2.0f * e_c);
            acc = fmaf(gate, v_c + e_c, acc);
            q_c = q_n; v_c = v_n; e_c = e_n;
            q_n = q_2; v_n = v_2; e_n = e_2;
        }
    }
    long off = (long)node * D + d;
    hnew[off] += acc;
}

// Legacy one-wave-per-node gather (fallback tiers).
template <bool PERM>
__global__ __launch_bounds__(256) void gather_kernel(
    const float* __restrict__ ea, const int* __restrict__ srcArr,
    const int* __restrict__ csr, const int* __restrict__ row_start,
    const float* __restrict__ We,
    const float* __restrict__ kb, const float* __restrict__ qb,
    const float* __restrict__ vb, float* __restrict__ hnew) {
    int d = threadIdx.x;
    int node = blockIdx.x * 4 + threadIdx.y;
    if (node >= N_NODES) return;
    float WeReg[E_IN];
#pragma unroll
    for (int i = 0; i < E_IN; ++i) WeReg[i] = We[i * D + d];
    int lo = row_start[node], hi = row_start[node + 1];
    float kv = kb[(long)node * D + d];
    float acc = 0.f;
    for (int base = lo; base < hi; base += 64) {
        int cnt = min(hi - base, 64);
        int e_l = 0, s_l = 0;
        if (d < cnt) {
            int p = base + d;
            e_l = PERM ? p : csr[p];
            s_l = PERM ? srcArr[p] : srcArr[e_l];
        }
        int s_c = __builtin_amdgcn_readlane(s_l, 0);
        int r_c = PERM ? base : __builtin_amdgcn_readlane(e_l, 0);
        float q_c = qb[(long)s_c * D + d];
        float v_c = vb[(long)s_c * D + d];
        float e_c = (d < E_IN) ? ea[(long)r_c * E_IN + d] : 0.f;
        for (int j = 0; j < cnt; ++j) {
            float q_n = 0.f, v_n = 0.f, e_n = 0.f;
            if (j + 1 < cnt) {
                int s_n = __builtin_amdgcn_readlane(s_l, j + 1);
                int r_n = PERM ? (base + j + 1) : __builtin_amdgcn_readlane(e_l, j + 1);
                q_n = qb[(long)s_n * D + d];
                v_n = vb[(long)s_n * D + d];
                e_n = (d < E_IN) ? ea[(long)r_n * E_IN + d] : 0.f;
            }
            float ed0 = 0.f, ed1 = 0.f;
#pragma unroll
            for (int i = 0; i < E_IN; i += 2) {
                ed0 = fmaf(bcast_f(e_c, i), WeReg[i], ed0);
                ed1 = fmaf(bcast_f(e_c, i + 1), WeReg[i + 1], ed1);
            }
            float ed = ed0 + ed1;
            float gate = silu_f(kv + q_c + 2.0f * ed);
            acc = fmaf(gate, v_c + ed, acc);
            q_c = q_n; v_c = v_n; e_c = e_n;
        }
    }
    long off = (long)node * D + d;
    hnew[off] += acc;
}

// per-column sum & sumsq
__global__ __launch_bounds__(256) void bn_stats_kernel(
    const float* __restrict__ hnew, float* __restrict__ stats) {
    int d = threadIdx.x, yy = threadIdx.y;
    float s = 0.f, s2 = 0.f;
    for (int n = blockIdx.x * 4 + yy; n < N_NODES; n += gridDim.x * 4) {
        float v = hnew[(long)n * D + d];
        s += v;
        s2 = fmaf(v, v, s2);
    }
    __shared__ float ls[4][D], ls2[4][D];
    ls[yy][d] = s; ls2[yy][d] = s2;
    __syncthreads();
    if (yy == 0) {
        atomicAdd(&stats[d],     ls[0][d] + ls[1][d] + ls[2][d] + ls[3][d]);
        atomicAdd(&stats[D + d], ls2[0][d] + ls2[1][d] + ls2[2][d] + ls2[3][d]);
    }
}

__global__ __launch_bounds__(256) void graph_bounds_kernel(
    const int* __restrict__ batch, int* __restrict__ start) {
    int n = blockIdx.x * 256 + threadIdx.x;
    if (n >= N_NODES) return;
    int b = batch[n];
    if (n == 0) {
        for (int g = 0; g <= b; ++g) start[g] = 0;
    } else {
        int p = batch[n - 1];
        for (int g = p + 1; g <= b; ++g) start[g] = n;
    }
    if (n == N_NODES - 1) {
        for (int g = b + 1; g <= N_GRAPHS; ++g) start[g] = N_NODES;
    }
}

// mean-pool(hnew) -> fused final-BN affine -> post FC + silu -> head
__global__ __launch_bounds__(256) void pool_head_kernel(
    const float* __restrict__ hnew, const int* __restrict__ start,
    const float* __restrict__ stats, const float* __restrict__ gamma,
    const float* __restrict__ beta,
    const float* __restrict__ pw, const float* __restrict__ pb,
    const float* __restrict__ ow, const float* __restrict__ ob,
    float* __restrict__ out) {
    int g = blockIdx.x;
    int d = threadIdx.x, yy = threadIdx.y;
    int lo = start[g], hi = start[g + 1];
    float s = 0.f;
    for (int n = lo + yy; n < hi; n += 4) s += hnew[(long)n * D + d];
    __shared__ float ls[4][D];
    ls[yy][d] = s;
    __syncthreads();
    __shared__ float grow[D];
    if (yy == 0) {
        float tot = ls[0][d] + ls[1][d] + ls[2][d] + ls[3][d];
        float gd = 0.f;
        if (hi > lo) {
            float m = tot / (float)(hi - lo);
            const float invN = 1.0f / (float)N_NODES;
            float mean = stats[d] * invN;
            float var = stats[D + d] * invN - mean * mean;
            float sc = rsqrtf(var + BN_EPS) * gamma[d];
            gd = (m - mean) * sc + beta[d];
        }
        grow[d] = gd;
    }
    __syncthreads();
    if (yy != 0) return;
    float accp = pb[d];
#pragma unroll 8
    for (int i = 0; i < D; ++i) accp = fmaf(grow[i], pw[i * D + d], accp);
    float sv = silu_f(accp) * ow[d];
    for (int off = 32; off > 0; off >>= 1) sv += __shfl_down(sv, off);
    if (d == 0) out[g] = sv + ob[0];
}

extern "C" void kernel_launch(void* const* d_in, const int* in_sizes, int n_in,
                              void* d_out, int out_size, void* d_ws, size_t ws_size,
                              hipStream_t stream) {
    const float* x        = (const float*)d_in[0];
    const int*   ei       = (const int*)d_in[1];
    const float* ea       = (const float*)d_in[2];
    const int*   batch    = (const int*)d_in[3];
    const float* pre_w    = (const float*)d_in[4];
    const float* pre_b    = (const float*)d_in[5];
    const float* Wk       = (const float*)d_in[6];
    const float* bk       = (const float*)d_in[7];
    const float* Wq       = (const float*)d_in[8];
    const float* bq       = (const float*)d_in[9];
    const float* Wv       = (const float*)d_in[10];
    const float* bv       = (const float*)d_in[11];
    const float* We       = (const float*)d_in[12];
    const float* Wskip    = (const float*)d_in[13];
    const float* conv_bias= (const float*)d_in[14];
    const float* bn_gamma = (const float*)d_in[15];
    const float* bn_beta  = (const float*)d_in[16];
    const float* post_w   = (const float*)d_in[17];
    const float* post_b   = (const float*)d_in[18];
    const float* out_w    = (const float*)d_in[19];
    const float* out_b    = (const float*)d_in[20];

    char* base = (char*)d_ws;
    float* ws = (float*)d_ws;
    const size_t NH = (size_t)N_NODES * D;
    float* bufA  = ws;
    float* bufB  = ws + NH;
    float* kb    = ws + 2 * NH;
    float* qb    = ws + 3 * NH;
    float* vb    = ws + 4 * NH;
    float* stats = ws + 5 * NH;                          // 3 * 2*D floats
    int*   start     = (int*)(stats + 6 * D);            // N_GRAPHS+1
    int*   deg       = start + (N_GRAPHS + 1);           // N_NODES
    int*   row_start = deg + N_NODES;                    // N_NODES+1
    int*   cursor    = row_start + (N_NODES + 1);        // N_NODES
    int*   partials  = cursor + N_NODES;                 // 128
    int*   posb      = partials + 128;                   // N_EDGES (within -> pos | csr)

    size_t off_e = (size_t)((char*)(posb + N_EDGES) - base);
    off_e = (off_e + 255) & ~(size_t)255;

    // Tier F (fused perm+emb): src_s + FULL em buffer. No ea_s copy at all.
    size_t em_offF = (off_e + (size_t)N_EDGES * sizeof(int) + 255) & ~(size_t)255;
    size_t needF = em_offF + (size_t)N_EDGES * D * sizeof(float);
    bool tierF = ws_size >= needF;
    // Tier 1: stride-50 ea_s + src_s (round-0 proven footprint)
    size_t src_off1 = off_e + (size_t)N_EDGES * E_IN * sizeof(float);
    bool tier1 = !tierF && (ws_size >= src_off1 + (size_t)N_EDGES * sizeof(int));

    const int* srcIdx = ei;
    const int* dstIdx = ei + N_EDGES;

    dim3 blk(64, 4);
    const int NB_N = (N_NODES + 3) / 4;

    // permutation / CSR build (deg+within in one atomic pass)
    hipMemsetAsync(deg, 0, N_NODES * sizeof(int), stream);
    hipMemsetAsync(stats, 0, 6 * D * sizeof(float), stream);
    deg_within_kernel<<<1024, 256, 0, stream>>>(dstIdx, deg, posb);
    scan_sum_kernel<<<SCAN_NCH, SCAN_BLK, 0, stream>>>(deg, partials);
    scan_part_kernel<<<1, 128, 0, stream>>>(partials);
    scan_write_kernel<<<SCAN_NCH, SCAN_BLK, 0, stream>>>(deg, partials, row_start, cursor);

    int*   srcF = (int*)(base + off_e);
    float* emF  = (float*)(base + em_offF);
    float* ea1  = (float*)(base + off_e);
    int*   src1 = (int*)(base + src_off1);

    if (tierF) {
        pos_fin_kernel<<<1024, 256, 0, stream>>>(srcIdx, dstIdx, row_start, posb, srcF);
    } else if (tier1) {
        scatter_perm_kernel<E_IN><<<(N_EDGES + 3) / 4, blk, 0, stream>>>(
            srcIdx, dstIdx, ea, cursor, ea1, src1);
    } else {
        scatter_kernel<<<1024, 256, 0, stream>>>(dstIdx, cursor, posb);
    }

    pre_fc_kernel<<<NB_N, blk, 0, stream>>>(x, pre_w, pre_b, bufA);

    float* hin = bufA;
    float* hout = bufB;
    for (int l = 0; l < N_LAYERS; ++l) {
        if (l == 0)
            proj_kernel<false><<<NB_N, blk, 0, stream>>>(
                hin, nullptr, nullptr, nullptr,
                Wk + l * D * D, bk + l * D, Wq + l * D * D, bq + l * D,
                Wv + l * D * D, bv + l * D, Wskip + l * D * D, conv_bias + l * D,
                kb, qb, vb, hout);
        else
            proj_kernel<true><<<NB_N, blk, 0, stream>>>(
                hin, stats + (l - 1) * 2 * D, bn_gamma + (l - 1) * D, bn_beta + (l - 1) * D,
                Wk + l * D * D, bk + l * D, Wq + l * D * D, bq + l * D,
                Wv + l * D * D, bv + l * D, Wskip + l * D * D, conv_bias + l * D,
                kb, qb, vb, hout);
        if (tierF) {
            edge_emb_perm_kernel<<<N_EDGES / EMB_TILE, 256, 0, stream>>>(
                ea, posb, We + l * E_IN * D, emF);
            gather_em_kernel<<<NB_N, blk, 0, stream>>>(
                emF, srcF, row_start, kb, qb, vb, hout);
        } else if (tier1) {
            gather_kernel<true><<<NB_N, blk, 0, stream>>>(
                ea1, src1, posb, row_start, We + l * E_IN * D, kb, qb, vb, hout);
        } else {
            gather_kernel<false><<<NB_N, blk, 0, stream>>>(
                ea, srcIdx, posb, row_start, We + l * E_IN * D, kb, qb, vb, hout);
        }
        bn_stats_kernel<<<256, blk, 0, stream>>>(hout, stats + l * 2 * D);
        float* t = hin; hin = hout; hout = t;
    }

    graph_bounds_kernel<<<(N_NODES + 255) / 256, 256, 0, stream>>>(batch, start);
    pool_head_kernel<<<N_GRAPHS, blk, 0, stream>>>(
        hin, start, stats + (N_LAYERS - 1) * 2 * D,
        bn_gamma + (N_LAYERS - 1) * D, bn_beta + (N_LAYERS - 1) * D,
        post_w, post_b, out_w, out_b, (float*)d_out);
}